// Round 1
// baseline (119.339 us; speedup 1.0000x reference)
//
#include <hip/hip_runtime.h>
#include <hip/hip_bf16.h>

#define SEQ 128
#define DM 32

// ---------------------------------------------------------------------------
// Kernel 0: fold all weight matrices into 4 scalars.
//   qw = Wt@Wq, qb = bt@Wq + bq   (likewise kw,kb,vw,vb)
//   a = (qw.kw)/sqrt(D), c = (qb.kw)/sqrt(D)
//   alpha = vw.Wo, beta = vb.Wo + bo
// Single wave; lanes 0..31 each own one output column e.
// ---------------------------------------------------------------------------
__global__ void precompute_consts(const float* __restrict__ Wt,
                                  const float* __restrict__ bt,
                                  const float* __restrict__ Wq,
                                  const float* __restrict__ bq,
                                  const float* __restrict__ Wk,
                                  const float* __restrict__ bk,
                                  const float* __restrict__ Wv,
                                  const float* __restrict__ bv,
                                  const float* __restrict__ Wo,
                                  const float* __restrict__ bo,
                                  float* __restrict__ consts) {
    int e = threadIdx.x;  // 0..63
    float qw = 0.f, qb = 0.f, kw = 0.f, kb = 0.f, vw = 0.f, vb = 0.f;
    float wo = 0.f;
    if (e < DM) {
        for (int d = 0; d < DM; ++d) {
            float wt = Wt[d];
            float bb = bt[d];
            qw = fmaf(wt, Wq[d * DM + e], qw);
            qb = fmaf(bb, Wq[d * DM + e], qb);
            kw = fmaf(wt, Wk[d * DM + e], kw);
            kb = fmaf(bb, Wk[d * DM + e], kb);
            vw = fmaf(wt, Wv[d * DM + e], vw);
            vb = fmaf(bb, Wv[d * DM + e], vb);
        }
        qb += bq[e];
        kb += bk[e];
        vb += bv[e];
        wo = Wo[e];  // Wo is (32,1) -> flat index e
    }
    float pa = qw * kw;   // -> a * sqrt(D)
    float pc = qb * kw;   // -> c * sqrt(D)
    float pal = vw * wo;  // -> alpha
    float pbe = vb * wo;  // -> beta - bo
    // full-wave sum (lanes >= 32 contribute zeros)
    for (int off = 32; off > 0; off >>= 1) {
        pa  += __shfl_down(pa, off);
        pc  += __shfl_down(pc, off);
        pal += __shfl_down(pal, off);
        pbe += __shfl_down(pbe, off);
    }
    if (e == 0) {
        const float inv_scale = 0.17677669529663687f;  // 1/sqrt(32)
        consts[0] = pa * inv_scale;   // a
        consts[1] = pc * inv_scale;   // c
        consts[2] = pal;              // alpha
        consts[3] = pbe + bo[0];      // beta
    }
}

// ---------------------------------------------------------------------------
// Main kernel: one wave per row of x. Each lane owns q = lane and q = lane+64,
// loops over all 128 k reading the row from LDS (broadcast, conflict-free).
//   t_q = a*x_q + c;  w = softmax_k(t_q * x_k);  m_q = sum_k w*x_k
//   out[b] = alpha * mean_q(m_q) + beta
// Exact stable-softmax shift: max_k(t*x_k) = max(t*xmax, t*xmin).
// ---------------------------------------------------------------------------
#define ROWS_PER_BLOCK 4

__global__ __launch_bounds__(256) void attn_rowmean_kernel(
        const float* __restrict__ x,
        const float* __restrict__ consts,
        float* __restrict__ out, int B) {
    __shared__ float sx[ROWS_PER_BLOCK][SEQ];

    const int wave = threadIdx.x >> 6;
    const int lane = threadIdx.x & 63;
    int b = blockIdx.x * ROWS_PER_BLOCK + wave;
    if (b >= B) b = B - 1;  // duplicate work on tail; writes are idempotent

    const float a     = consts[0];
    const float c     = consts[1];
    const float alpha = consts[2];
    const float beta  = consts[3];

    const float* xr = x + (size_t)b * SEQ;
    const float x0 = xr[lane];
    const float x1 = xr[lane + 64];
    sx[wave][lane]      = x0;
    sx[wave][lane + 64] = x1;

    // row max/min via wave butterfly
    float mx = fmaxf(x0, x1);
    float mn = fminf(x0, x1);
    for (int off = 32; off > 0; off >>= 1) {
        mx = fmaxf(mx, __shfl_xor(mx, off));
        mn = fminf(mn, __shfl_xor(mn, off));
    }

    __syncthreads();  // LDS row visibility

    const float t0 = fmaf(a, x0, c);
    const float t1 = fmaf(a, x1, c);
    const float m0 = fmaxf(t0 * mx, t0 * mn);  // exact max_k of t0*x_k
    const float m1 = fmaxf(t1 * mx, t1 * mn);

    float s0 = 0.f, sxw0 = 0.f;
    float s1 = 0.f, sxw1 = 0.f;

    const float4* row4 = (const float4*)sx[wave];
#pragma unroll
    for (int k4 = 0; k4 < SEQ / 4; ++k4) {
        const float4 xv = row4[k4];  // ds_read_b128, broadcast
        float e;
        e = __expf(fmaf(t0, xv.x, -m0)); s0 += e; sxw0 = fmaf(e, xv.x, sxw0);
        e = __expf(fmaf(t0, xv.y, -m0)); s0 += e; sxw0 = fmaf(e, xv.y, sxw0);
        e = __expf(fmaf(t0, xv.z, -m0)); s0 += e; sxw0 = fmaf(e, xv.z, sxw0);
        e = __expf(fmaf(t0, xv.w, -m0)); s0 += e; sxw0 = fmaf(e, xv.w, sxw0);
        e = __expf(fmaf(t1, xv.x, -m1)); s1 += e; sxw1 = fmaf(e, xv.x, sxw1);
        e = __expf(fmaf(t1, xv.y, -m1)); s1 += e; sxw1 = fmaf(e, xv.y, sxw1);
        e = __expf(fmaf(t1, xv.z, -m1)); s1 += e; sxw1 = fmaf(e, xv.z, sxw1);
        e = __expf(fmaf(t1, xv.w, -m1)); s1 += e; sxw1 = fmaf(e, xv.w, sxw1);
    }

    // m_q for this lane's two q values, then mean over all 128 q in the row
    float msum = sxw0 / s0 + sxw1 / s1;
    for (int off = 32; off > 0; off >>= 1)
        msum += __shfl_xor(msum, off);

    if (lane == 0)
        out[b] = fmaf(alpha, msum * (1.0f / 128.0f), beta);
}

extern "C" void kernel_launch(void* const* d_in, const int* in_sizes, int n_in,
                              void* d_out, int out_size, void* d_ws, size_t ws_size,
                              hipStream_t stream) {
    const float* x  = (const float*)d_in[0];
    const float* Wt = (const float*)d_in[1];
    const float* bt = (const float*)d_in[2];
    const float* Wq = (const float*)d_in[3];
    const float* bq = (const float*)d_in[4];
    const float* Wk = (const float*)d_in[5];
    const float* bk = (const float*)d_in[6];
    const float* Wv = (const float*)d_in[7];
    const float* bv = (const float*)d_in[8];
    const float* Wo = (const float*)d_in[9];
    const float* bo = (const float*)d_in[10];
    float* out = (float*)d_out;
    float* consts = (float*)d_ws;  // 4 floats

    const int B = in_sizes[0] / SEQ;

    precompute_consts<<<1, 64, 0, stream>>>(Wt, bt, Wq, bq, Wk, bk, Wv, bv,
                                            Wo, bo, consts);

    const int grid = (B + ROWS_PER_BLOCK - 1) / ROWS_PER_BLOCK;
    attn_rowmean_kernel<<<grid, 256, 0, stream>>>(x, consts, out, B);
}

// Round 2
// 98.398 us; speedup vs baseline: 1.2128x; 1.2128x over previous
//
#include <hip/hip_runtime.h>
#include <hip/hip_bf16.h>

#define SEQ 128
#define DM 32

// log2(e) * 2^23 : converts natural-exponent slope directly into float-exponent bits
#define K_LOG2E_2P23 12102203.161561485f
// Schraudolph bias: (127 - 0.04384) * 2^23, minimax-balanced relative error (+/- ~3%)
#define SCHRAUDOLPH_C 1064985472.0f

// ---------------------------------------------------------------------------
// Kernel 0: fold all weight matrices into 4 scalars.
//   qw = Wt@Wq, qb = bt@Wq + bq (likewise k,v)
//   a = (qw.kw)/sqrt(D), c = (qb.kw)/sqrt(D)
//   alpha = vw.Wo, beta = vb.Wo + bo
// Stored pre-scaled: A = a*log2e*2^23, C = c*log2e*2^23 so the main loop's
// fmaf lands directly in float-exponent-bit units.
// ---------------------------------------------------------------------------
__global__ void precompute_consts(const float* __restrict__ Wt,
                                  const float* __restrict__ bt,
                                  const float* __restrict__ Wq,
                                  const float* __restrict__ bq,
                                  const float* __restrict__ Wk,
                                  const float* __restrict__ bk,
                                  const float* __restrict__ Wv,
                                  const float* __restrict__ bv,
                                  const float* __restrict__ Wo,
                                  const float* __restrict__ bo,
                                  float* __restrict__ consts) {
    int e = threadIdx.x;  // 0..63
    float qw = 0.f, qb = 0.f, kw = 0.f, kb = 0.f, vw = 0.f, vb = 0.f;
    float wo = 0.f;
    if (e < DM) {
        for (int d = 0; d < DM; ++d) {
            float wt = Wt[d];
            float bb = bt[d];
            qw = fmaf(wt, Wq[d * DM + e], qw);
            qb = fmaf(bb, Wq[d * DM + e], qb);
            kw = fmaf(wt, Wk[d * DM + e], kw);
            kb = fmaf(bb, Wk[d * DM + e], kb);
            vw = fmaf(wt, Wv[d * DM + e], vw);
            vb = fmaf(bb, Wv[d * DM + e], vb);
        }
        qb += bq[e];
        kb += bk[e];
        vb += bv[e];
        wo = Wo[e];  // Wo is (32,1) -> flat index e
    }
    float pa = qw * kw;   // -> a * sqrt(D)
    float pc = qb * kw;   // -> c * sqrt(D)
    float pal = vw * wo;  // -> alpha
    float pbe = vb * wo;  // -> beta - bo
    for (int off = 32; off > 0; off >>= 1) {
        pa  += __shfl_down(pa, off);
        pc  += __shfl_down(pc, off);
        pal += __shfl_down(pal, off);
        pbe += __shfl_down(pbe, off);
    }
    if (e == 0) {
        const float inv_scale = 0.17677669529663687f;  // 1/sqrt(32)
        consts[0] = pa * inv_scale * K_LOG2E_2P23;  // A  (exponent-bit units)
        consts[1] = pc * inv_scale * K_LOG2E_2P23;  // C  (exponent-bit units)
        consts[2] = pal;                            // alpha
        consts[3] = pbe + bo[0];                    // beta
    }
}

// ---------------------------------------------------------------------------
// Inner loop: Schraudolph fast-exp softmax weighted mean.
//   e_k = 2^{(T*x_k - m)/2^23} approx by bitcast(int(fmaf(T, x_k, M)))
// CLAMP guards against arg < -126.9*2^23 (negative int -> garbage float).
// Fast path (wave-uniform check) omits the clamp: 4 VALU ops per (q,k).
// ---------------------------------------------------------------------------
template <bool CLAMP>
__device__ __forceinline__ void row_loop(const float4* __restrict__ row4,
                                         float T0, float M0, float T1, float M1,
                                         float& s0, float& sxw0,
                                         float& s1, float& sxw1) {
#pragma unroll
    for (int k4 = 0; k4 < SEQ / 4; ++k4) {
        const float4 xv = row4[k4];  // ds_read_b128, all-lane broadcast
#pragma unroll
        for (int j = 0; j < 4; ++j) {
            const float xk = (j == 0) ? xv.x : (j == 1) ? xv.y : (j == 2) ? xv.z : xv.w;
            float v0 = fmaf(T0, xk, M0);
            float v1 = fmaf(T1, xk, M1);
            if (CLAMP) {
                v0 = fmaxf(v0, 0.0f);
                v1 = fmaxf(v1, 0.0f);
            }
            const float e0 = __int_as_float((int)v0);
            const float e1 = __int_as_float((int)v1);
            s0 += e0; sxw0 = fmaf(e0, xk, sxw0);
            s1 += e1; sxw1 = fmaf(e1, xk, sxw1);
        }
    }
}

#define ROWS_PER_BLOCK 4

__global__ __launch_bounds__(256) void attn_rowmean_kernel(
        const float* __restrict__ x,
        const float* __restrict__ consts,
        float* __restrict__ out, int B) {
    __shared__ float sx[ROWS_PER_BLOCK][SEQ];

    const int wave = threadIdx.x >> 6;
    const int lane = threadIdx.x & 63;
    int b = blockIdx.x * ROWS_PER_BLOCK + wave;
    if (b >= B) b = B - 1;  // duplicate tail work; idempotent writes

    const float A     = consts[0];
    const float C     = consts[1];
    const float alpha = consts[2];
    const float beta  = consts[3];

    const float* xr = x + (size_t)b * SEQ;
    const float x0 = xr[lane];
    const float x1 = xr[lane + 64];
    sx[wave][lane]      = x0;
    sx[wave][lane + 64] = x1;

    // row max/min via wave butterfly
    float mx = fmaxf(x0, x1);
    float mn = fminf(x0, x1);
    for (int off = 32; off > 0; off >>= 1) {
        mx = fmaxf(mx, __shfl_xor(mx, off));
        mn = fminf(mn, __shfl_xor(mn, off));
    }

    __syncthreads();  // LDS row visibility

    // T_q in exponent-bit units; M_q = bias - max_k(T_q * x_k)
    const float T0 = fmaf(A, x0, C);
    const float T1 = fmaf(A, x1, C);
    const float m0 = fmaxf(T0 * mx, T0 * mn);
    const float m1 = fmaxf(T1 * mx, T1 * mn);
    const float M0 = SCHRAUDOLPH_C - m0;
    const float M1 = SCHRAUDOLPH_C - m1;

    float s0 = 0.f, sxw0 = 0.f, s1 = 0.f, sxw1 = 0.f;
    const float4* row4 = (const float4*)sx[wave];

    // Wave-uniform overflow-risk check: max|T| * span(x) vs ~126.9*2^23.
    const float maxabs = fmaxf(fabsf(mx), fabsf(mn));
    const float tmax = fmaf(fabsf(A), maxabs, fabsf(C));
    if (tmax * (mx - mn) < 1.0e9f) {
        row_loop<false>(row4, T0, M0, T1, M1, s0, sxw0, s1, sxw1);
    } else {
        row_loop<true>(row4, T0, M0, T1, M1, s0, sxw0, s1, sxw1);
    }

    // m_q for this lane's two q's, then mean over the row's 128 q.
    float msum = sxw0 * __builtin_amdgcn_rcpf(s0) +
                 sxw1 * __builtin_amdgcn_rcpf(s1);
    for (int off = 32; off > 0; off >>= 1)
        msum += __shfl_xor(msum, off);

    if (lane == 0)
        out[b] = fmaf(alpha, msum * (1.0f / 128.0f), beta);
}

extern "C" void kernel_launch(void* const* d_in, const int* in_sizes, int n_in,
                              void* d_out, int out_size, void* d_ws, size_t ws_size,
                              hipStream_t stream) {
    const float* x  = (const float*)d_in[0];
    const float* Wt = (const float*)d_in[1];
    const float* bt = (const float*)d_in[2];
    const float* Wq = (const float*)d_in[3];
    const float* bq = (const float*)d_in[4];
    const float* Wk = (const float*)d_in[5];
    const float* bk = (const float*)d_in[6];
    const float* Wv = (const float*)d_in[7];
    const float* bv = (const float*)d_in[8];
    const float* Wo = (const float*)d_in[9];
    const float* bo = (const float*)d_in[10];
    float* out = (float*)d_out;
    float* consts = (float*)d_ws;  // 4 floats

    const int B = in_sizes[0] / SEQ;

    precompute_consts<<<1, 64, 0, stream>>>(Wt, bt, Wq, bq, Wk, bk, Wv, bv,
                                            Wo, bo, consts);

    const int grid = (B + ROWS_PER_BLOCK - 1) / ROWS_PER_BLOCK;
    attn_rowmean_kernel<<<grid, 256, 0, stream>>>(x, consts, out, B);
}